// Round 4
// baseline (951.221 us; speedup 1.0000x reference)
//
#include <hip/hip_runtime.h>

#define BLOCK 256
#define TILE  1024              // records per block-iteration
#define NBLK  2048              // 8 blocks/CU * 256 CU, exactly resident, %8==0

typedef float f4 __attribute__((ext_vector_type(4)));
typedef int   i4 __attribute__((ext_vector_type(4)));

// ============================ DIAGNOSTIC ROUND (resubmit; R3 was an infra
// failure — "container failed twice" with no kernel verdict) =============
// v6 = v5 with DOUBLE COVERAGE: grid-strides over 2*n_tiles virtual tiles;
// virtual tile tv maps to actual tile tv % n_tiles. Every output chunk is
// written twice with identical correct values (idempotent -> absmax 0),
// from blocks ~800 MB apart in the sweep (L2 cannot absorb the duplicate:
// 805 MB >> 32 MB L2, line is evicted between the two writes).
// Purpose: headline_delta vs R2 == true gather-kernel duration; if that
// exceeds ~520 us the gather dispatch enters rocprof top-5 WITH counters.
// Revert to single coverage (v5) once measured.
// ==========================================================================
__device__ __forceinline__ void barrier_lgkm_only()
{
    asm volatile("s_waitcnt lgkmcnt(0)" ::: "memory");
    __builtin_amdgcn_s_barrier();
    asm volatile("" ::: "memory");
}

__device__ __forceinline__ i4 load_idx4(const int* __restrict__ rel_pos,
                                        unsigned int r, unsigned int n_rec)
{
    i4 rv;
    if (r + 3u < n_rec) {
        rv = *(const i4*)&rel_pos[r];          // coalesced dwordx4
    } else {
#pragma unroll
        for (int e = 0; e < 4; ++e)
            rv[e] = (r + (unsigned)e < n_rec) ? rel_pos[r + e] : 0;
    }
    return rv;
}

__global__ __launch_bounds__(BLOCK) void gather12_v6diag(
    const int* __restrict__ rel_pos,
    const float* __restrict__ W,        // [12][64] float32
    f4* __restrict__ out,
    unsigned int n_rec,
    unsigned int n_tiles_real,
    unsigned int n_tiles_virt)          // == 2 * n_tiles_real
{
    __shared__ float tab[64 * 12];      // tab[c*12+h] = W[h][c]; chunks 16B-aligned
    __shared__ int cls[2][TILE];        // double-buffered index tile

    const int t = threadIdx.x;

    // table: once per block (768 floats)
#pragma unroll
    for (int i = 0; i < 3; ++i) {
        int idx = t + i * BLOCK;        // 0..767
        tab[(idx & 63) * 12 + (idx >> 6)] = W[idx];
    }

    unsigned int tile = blockIdx.x;     // virtual tile id
    if (tile >= n_tiles_virt) return;   // block-uniform

    // prologue: stage tile0 indices into cls[0] (blockIdx < n_tiles_real always here)
    *(i4*)&cls[0][t * 4] = load_idx4(rel_pos, tile * TILE + (unsigned)t * 4u, n_rec);
    int cur = 0;

    const unsigned long long total_chunks = (unsigned long long)n_rec * 3ull;

    while (true) {
        const unsigned int next = tile + gridDim.x;          // virtual
        const bool have_next = (next < n_tiles_virt);        // block-uniform
        // actual tile for THIS iteration
        const unsigned int ta = (tile >= n_tiles_real) ? tile - n_tiles_real : tile;

        barrier_lgkm_only();            // cls[cur] (+tab on first pass) visible

        // prefetch next tile's indices into regs; no wait here
        i4 rv;
        if (have_next) {
            unsigned int na = (next >= n_tiles_real) ? next - n_tiles_real : next;
            rv = load_idx4(rel_pos, na * TILE + (unsigned)t * 4u, n_rec);
        }

        // gather + coalesced store: 3072 chunks, 12 per thread
        const unsigned long long chunkBase = (unsigned long long)ta * (TILE * 3ull);
        if ((unsigned long long)(ta + 1u) * TILE <= (unsigned long long)n_rec) {
            // full tile fast path: no per-chunk guard, pure store stream
#pragma unroll
            for (int k = 0; k < 12; ++k) {
                unsigned int j = (unsigned int)t + BLOCK * (unsigned int)k;
                unsigned int p = j / 3u;                 // const divisor -> magic mul
                unsigned int s = j - p * 3u;             // 0,1,2
                unsigned int c = (unsigned int)cls[cur][p];   // LDS broadcast x3
                out[chunkBase + j] = *(const f4*)(tab + c * 12u + 4u * s);
            }
        } else {
#pragma unroll
            for (int k = 0; k < 12; ++k) {
                unsigned int j = (unsigned int)t + BLOCK * (unsigned int)k;
                unsigned long long g = chunkBase + j;
                if (g < total_chunks) {
                    unsigned int p = j / 3u;
                    unsigned int s = j - p * 3u;
                    unsigned int c = (unsigned int)cls[cur][p];
                    out[g] = *(const f4*)(tab + c * 12u + 4u * s);
                }
            }
        }

        if (!have_next) break;
        // stage next tile into the other buffer (vmcnt wait on rv auto-inserted)
        *(i4*)&cls[cur ^ 1][t * 4] = rv;
        cur ^= 1;
        tile = next;
    }
}

extern "C" void kernel_launch(void* const* d_in, const int* in_sizes, int n_in,
                              void* d_out, int out_size, void* d_ws, size_t ws_size,
                              hipStream_t stream)
{
    const int* rel_pos = (const int*)d_in[0];
    // d_in[1] = hidden_states: unused (reference only uses its dtype)
    const float* W = (const float*)d_in[2];

    const unsigned int n_rec = (unsigned int)in_sizes[0];          // 4*2048*2048
    const unsigned int n_tiles = (n_rec + TILE - 1) / TILE;        // 16384
    const unsigned int n_virt = n_tiles * 2u;                      // double coverage
    const unsigned int blocks = (n_virt < NBLK) ? n_virt : NBLK;   // 2048

    gather12_v6diag<<<blocks, BLOCK, 0, stream>>>(rel_pos, W, (f4*)d_out,
                                                  n_rec, n_tiles, n_virt);
}

// Round 5
// 825.051 us; speedup vs baseline: 1.1529x; 1.1529x over previous
//
#include <hip/hip_runtime.h>

#define BLOCK 256
#define TILE  1024              // records per block-iteration
#define NBLK  2048              // 8 blocks/CU * 256 CU, exactly resident, %8==0

typedef float f4 __attribute__((ext_vector_type(4)));
typedef int   i4 __attribute__((ext_vector_type(4)));

// out[b,i,j,h] = W[h, rel_pos[b,i,j]] — float32 gather, 12 floats (3 x float4)/record.
// v5 FINAL (revert of the v6 double-coverage diagnostic).
// R4 diagnostic proved this kernel is at the HBM roofline:
//   double-coverage headline delta = 125 us for 872 MB of extra traffic
//   (805 MB out + 67 MB idx) vs 129-138 us floor at the 6.25-6.3 TB/s
//   measured achievable write BW -> >=96% of ceiling. The remaining
//   ~700 us of the headline is harness poison-fill (516 us) + dispatch churn.
// Structure:
//   - persistent grid (2048 blocks, 8/CU), table staged once per block;
//   - idx staged as int4 -> ds_write_b128, double-buffered cls[2][1024];
//   - ONE lgkm-only barrier per tile (raw s_barrier, no vmcnt drain:
//     stores stay in flight across barriers; only cross-wave state is LDS);
//   - gather: chunk j = t+256k, p=j/3 (magic mul), s=j%3, ds_read_b128 from
//     tab[cls[p]*12+4s], plain coalesced dwordx4 store.
__device__ __forceinline__ void barrier_lgkm_only()
{
    asm volatile("s_waitcnt lgkmcnt(0)" ::: "memory");
    __builtin_amdgcn_s_barrier();
    asm volatile("" ::: "memory");
}

__device__ __forceinline__ i4 load_idx4(const int* __restrict__ rel_pos,
                                        unsigned int r, unsigned int n_rec)
{
    i4 rv;
    if (r + 3u < n_rec) {
        rv = *(const i4*)&rel_pos[r];          // coalesced dwordx4
    } else {
#pragma unroll
        for (int e = 0; e < 4; ++e)
            rv[e] = (r + (unsigned)e < n_rec) ? rel_pos[r + e] : 0;
    }
    return rv;
}

__global__ __launch_bounds__(BLOCK) void gather12_v5(
    const int* __restrict__ rel_pos,
    const float* __restrict__ W,        // [12][64] float32
    f4* __restrict__ out,
    unsigned int n_rec,
    unsigned int n_tiles)
{
    __shared__ float tab[64 * 12];      // tab[c*12+h] = W[h][c]; chunks 16B-aligned
    __shared__ int cls[2][TILE];        // double-buffered index tile

    const int t = threadIdx.x;

    // table: once per block (768 floats)
#pragma unroll
    for (int i = 0; i < 3; ++i) {
        int idx = t + i * BLOCK;        // 0..767
        tab[(idx & 63) * 12 + (idx >> 6)] = W[idx];
    }

    unsigned int tile = blockIdx.x;
    if (tile >= n_tiles) return;        // block-uniform

    // prologue: stage tile0 indices into cls[0]
    *(i4*)&cls[0][t * 4] = load_idx4(rel_pos, tile * TILE + (unsigned)t * 4u, n_rec);
    int cur = 0;

    const unsigned long long total_chunks = (unsigned long long)n_rec * 3ull;

    while (true) {
        const unsigned int next = tile + gridDim.x;
        const bool have_next = (next < n_tiles);        // block-uniform

        barrier_lgkm_only();            // cls[cur] (+tab on first pass) visible

        // prefetch next tile's indices into regs; no wait here
        i4 rv;
        if (have_next)
            rv = load_idx4(rel_pos, next * TILE + (unsigned)t * 4u, n_rec);

        // gather + coalesced store: 3072 chunks, 12 per thread
        const unsigned long long chunkBase = (unsigned long long)tile * (TILE * 3ull);
        if ((unsigned long long)(tile + 1u) * TILE <= (unsigned long long)n_rec) {
            // full tile fast path: no per-chunk guard, pure store stream
#pragma unroll
            for (int k = 0; k < 12; ++k) {
                unsigned int j = (unsigned int)t + BLOCK * (unsigned int)k;
                unsigned int p = j / 3u;                 // const divisor -> magic mul
                unsigned int s = j - p * 3u;             // 0,1,2
                unsigned int c = (unsigned int)cls[cur][p];   // LDS broadcast x3
                out[chunkBase + j] = *(const f4*)(tab + c * 12u + 4u * s);
            }
        } else {
#pragma unroll
            for (int k = 0; k < 12; ++k) {
                unsigned int j = (unsigned int)t + BLOCK * (unsigned int)k;
                unsigned long long g = chunkBase + j;
                if (g < total_chunks) {
                    unsigned int p = j / 3u;
                    unsigned int s = j - p * 3u;
                    unsigned int c = (unsigned int)cls[cur][p];
                    out[g] = *(const f4*)(tab + c * 12u + 4u * s);
                }
            }
        }

        if (!have_next) break;
        // stage next tile into the other buffer (vmcnt wait on rv auto-inserted)
        *(i4*)&cls[cur ^ 1][t * 4] = rv;
        cur ^= 1;
        tile = next;
    }
}

extern "C" void kernel_launch(void* const* d_in, const int* in_sizes, int n_in,
                              void* d_out, int out_size, void* d_ws, size_t ws_size,
                              hipStream_t stream)
{
    const int* rel_pos = (const int*)d_in[0];
    // d_in[1] = hidden_states: unused (reference only uses its dtype)
    const float* W = (const float*)d_in[2];

    const unsigned int n_rec = (unsigned int)in_sizes[0];          // 4*2048*2048
    const unsigned int n_tiles = (n_rec + TILE - 1) / TILE;        // 16384
    const unsigned int blocks = (n_tiles < NBLK) ? n_tiles : NBLK; // 2048

    gather12_v5<<<blocks, BLOCK, 0, stream>>>(rel_pos, W, (f4*)d_out, n_rec, n_tiles);
}